// Round 11
// baseline (144.651 us; speedup 1.0000x reference)
//
#include <hip/hip_runtime.h>

typedef __bf16 bf16x8 __attribute__((ext_vector_type(8)));
typedef __bf16 bf16x2 __attribute__((ext_vector_type(2)));
typedef float  f32x4  __attribute__((ext_vector_type(4)));
typedef float  f32x16 __attribute__((ext_vector_type(16)));
typedef unsigned short u16;
typedef unsigned u32x2 __attribute__((ext_vector_type(2)));
typedef unsigned u32x4 __attribute__((ext_vector_type(4)));

// native RNE f32->bf16 (compiler emits v_cvt_pk_bf16_f32)
__device__ __forceinline__ u16 f2bf(float f) {
  return __builtin_bit_cast(u16, (__bf16)f);
}
// pack two f32 -> dword of 2 bf16 (lo = bits 0-15)
__device__ __forceinline__ unsigned pack2(float lo, float hi) {
  bf16x2 t;
  t[0] = (__bf16)lo; t[1] = (__bf16)hi;
  return __builtin_bit_cast(unsigned, t);
}

#define GLOAD16(g, l) __builtin_amdgcn_global_load_lds( \
    (__attribute__((address_space(1))) void*)(void*)(g), \
    (__attribute__((address_space(3))) void*)(l), 16, 0, 0)

// log2(e)/8 : folds softmax scale (1/sqrt(64)) and exp->exp2 conversion into Q
#define QSCALE 0.18033688011112042f

// ---------------------------------------------------------------- converts
// single segmented launch (boundaries block-uniform: 3072 / 864 / 288 blocks)
__global__ __launch_bounds__(256) void cvt_all(
    const float* __restrict__ x, const float* __restrict__ wq,
    const float* __restrict__ wp, unsigned* __restrict__ xb,
    unsigned* __restrict__ wqb, unsigned* __restrict__ wpb) {
  int i = blockIdx.x * 256 + threadIdx.x;
  const float* src;
  unsigned* dst;
  if (i < 786432) {                 // x: 6291456 f32 = 786432 vec8
    src = x; dst = xb;
  } else if (i < 786432 + 221184) { // Wqkv: 1769472 f32
    src = wq; dst = wqb; i -= 786432;
  } else {                          // Wproj: 589824 f32
    src = wp; dst = wpb; i -= 786432 + 221184;
  }
  const float4* s = (const float4*)src + 2 * (size_t)i;
  float4 a = s[0], b = s[1];
  u32x4 o = {pack2(a.x, a.y), pack2(a.z, a.w), pack2(b.x, b.y), pack2(b.z, b.w)};
  *((u32x4*)dst + i) = o;
}

// ---------------------------------------------------------------- GEMM (TN)
// C[m][n] = sum_k A[m][k]*B[n][k]; 128x128 tile, BK=32, double-buffered LDS,
// one barrier per K-step (stage(next) overlaps compute(cur)).
template<int EPI>
__global__ __launch_bounds__(256) void gemm_tn(
    const u16* __restrict__ A, const u16* __restrict__ B,
    const float* __restrict__ bias, float* __restrict__ outF,
    u16* __restrict__ qws, u16* __restrict__ kws, u16* __restrict__ vtws,
    int M, int N, int K) {
  __shared__ __align__(16) u16 As[8192];   // 2 x [128][32]
  __shared__ __align__(16) u16 Bs[8192];
  const int tid = threadIdx.x;
  const int ln = tid & 63, wv = tid >> 6;
  const int wr = wv >> 1, wc = wv & 1;
  const int m0 = blockIdx.x * 128, n0 = blockIdx.y * 128;

  f32x4 acc[4][4] = {};

  const int c0 = tid, c1 = tid + 256;
  const int r0 = c0 >> 2, kc0 = ((c0 & 3) ^ ((r0 >> 1) & 3)) * 8;
  const int r1 = c1 >> 2, kc1 = ((c1 & 3) ^ ((r1 >> 1) & 3)) * 8;
  const u16* ag0 = A + (size_t)(m0 + r0) * K + kc0;
  const u16* ag1 = A + (size_t)(m0 + r1) * K + kc1;
  const u16* bg0 = B + (size_t)(n0 + r0) * K + kc0;
  const u16* bg1 = B + (size_t)(n0 + r1) * K + kc1;

  // prologue: stage k0=0 into buffer 0
  GLOAD16(ag0, As + wv * 512);
  GLOAD16(ag1, As + 2048 + wv * 512);
  GLOAD16(bg0, Bs + wv * 512);
  GLOAD16(bg1, Bs + 2048 + wv * 512);
  __syncthreads();

  int cur = 0;
  for (int k0 = 0; k0 < K; k0 += 32) {
    const int nxt = cur ^ 1;
    if (k0 + 32 < K) {
      GLOAD16(ag0 + k0 + 32, As + nxt * 4096 + wv * 512);
      GLOAD16(ag1 + k0 + 32, As + nxt * 4096 + 2048 + wv * 512);
      GLOAD16(bg0 + k0 + 32, Bs + nxt * 4096 + wv * 512);
      GLOAD16(bg1 + k0 + 32, Bs + nxt * 4096 + 2048 + wv * 512);
    }
    const u16* ab = As + cur * 4096;
    const u16* bb = Bs + cur * 4096;
    bf16x8 af[4], bfr[4];
#pragma unroll
    for (int i = 0; i < 4; ++i) {
      int ra = wr * 64 + i * 16 + (ln & 15);
      af[i] = *(const bf16x8*)(ab + ra * 32 + (((ln >> 4) ^ ((ra >> 1) & 3)) * 8));
      int rb = wc * 64 + i * 16 + (ln & 15);
      bfr[i] = *(const bf16x8*)(bb + rb * 32 + (((ln >> 4) ^ ((rb >> 1) & 3)) * 8));
    }
#pragma unroll
    for (int i = 0; i < 4; ++i)
#pragma unroll
      for (int j = 0; j < 4; ++j)
        acc[i][j] = __builtin_amdgcn_mfma_f32_16x16x32_bf16(af[i], bfr[j], acc[i][j], 0, 0, 0);
    __syncthreads();
    cur = nxt;
  }

  if (EPI == 1) {
#pragma unroll
    for (int j = 0; j < 4; ++j) {
      int col = n0 + wc * 64 + j * 16 + (ln & 15);
      float bj = bias[col];
#pragma unroll
      for (int i = 0; i < 4; ++i) {
        int mr = m0 + wr * 64 + i * 16 + ((ln >> 4) << 2);
#pragma unroll
        for (int r = 0; r < 4; ++r)
          outF[(size_t)(mr + r) * N + col] = acc[i][j][r] + bj;
      }
    }
  } else {
    const int s = n0 / 768;  // 0=q 1=k 2=v (block-uniform; 768%128==0)
#pragma unroll
    for (int j = 0; j < 4; ++j) {
      int col = n0 + wc * 64 + j * 16 + (ln & 15);
      float bj = bias[col];
      int ns = col - s * 768;
      int h = ns >> 6, d = ns & 63;
#pragma unroll
      for (int i = 0; i < 4; ++i) {
        int m = m0 + wr * 64 + i * 16 + ((ln >> 4) << 2);
        int b = m >> 11, iseq = m & 2047;
        size_t bh = (size_t)(b * 12 + h);
        if (s == 0) {
#pragma unroll
          for (int r = 0; r < 4; ++r)
            qws[(bh * 2048 + iseq + r) * 64 + d] = f2bf((acc[i][j][r] + bj) * QSCALE);
        } else if (s == 1) {
#pragma unroll
          for (int r = 0; r < 4; ++r)
            kws[(bh * 2048 + iseq + r) * 64 + d] = f2bf(acc[i][j][r] + bj);
        } else {
          // V^T in LDS-READY layout: [bh][tile=k>>5][wc=(k>>3)&3][d][j=k&7].
          // Each 32-kv tile is a contiguous 4KB blob whose linear order is
          // exactly what attn's global_load_lds staging needs (dest linear,
          // source linear, fully coalesced both sides).
          u32x2 pk = {pack2(acc[i][j][0] + bj, acc[i][j][1] + bj),
                      pack2(acc[i][j][2] + bj, acc[i][j][3] + bj)};
          *(u32x2*)(vtws + ((size_t)bh * 64 + (iseq >> 5)) * 2048 +
                    ((iseq >> 3) & 3) * 512 + (size_t)d * 8 + (iseq & 7)) = pk;
        }
      }
    }
  }
}

// ---------------------------------------------------------------- flash attn
// R11: occupancy unlock. R10 revealed the true register footprint: R4's "84
// VGPR" excludes 64 AGPRs of accumulator (unified file) -> ~148 regs/wave ->
// hard 3 waves/SIMD; and grid 768 = 3 blocks/CU capped TLP at 12 waves/CU.
// All R5/R9 nulls happened inside this ceiling. Fix both without losing the
// shared-staging property (R8/R10 lesson: sharing > barrier-removal):
//   - wave = 32 q (ONE 32-col group) x 1024 KV -> acc 32 regs, total ~110
//     < 128 -> 4 waves/SIMD possible.
//   - QBLK = 64 -> grid (32,48) = 1536 blocks = 6/CU; residency-capped at
//     4 blocks/CU (LDS 33KB) -> 16 waves/CU steady state (+33% TLP).
//   - staging/layouts IDENTICAL to R4/R7 (pair p stages K+V via its 2 qw
//     waves; pi-permuted K rows; LDS-ready V; XOR-swizzled K chunks).
//   Cost: each K/V fragment feeds 1 q-group (LDS reads x2 — pipe has 4x
//   headroom: ~35K of 150K cy) and a finer drain tail.
// Math unchanged: swapped-operand 32x32x16 S^T = mfma(K,Q^T); exp2
// shift-invariant softmax (no max); VALU denominator; in-lane P pack via pi;
// KV halves combined by plain (O,l) addition via LDS exchange.
__global__ __launch_bounds__(256, 4) void attn_fa(
    const u16* __restrict__ qws, const u16* __restrict__ kws,
    const u16* __restrict__ vtws, u16* __restrict__ aows) {
  __shared__ __align__(16) u16 SM[16384];  // K: [p][buf][2048] | V: 8192 + same
  const int tid = threadIdx.x, ln = tid & 63, wv = tid >> 6;
  const int lq = ln & 31, hi = ln >> 5;
  const int qw = wv & 1;        // which 32-q chunk of the block's 64 q
  const int p  = wv >> 1;       // which KV half

  // XCD-chunked swizzle: flat = y*32+x; xcd = flat&7 owns bh in [6*xcd,6*xcd+6)
  const int flat = blockIdx.y * 32 + blockIdx.x;
  const int xcd = flat & 7, jj = flat >> 3;        // jj 0..191
  const int bh = xcd * 6 + (jj % 6);
  const int q0 = (jj / 6) * 64 + qw * 32;          // 32 q-tiles of 64

  const int kv0 = p * 1024;
  const size_t kbase = (size_t)bh * 2048 * 64;   // Q/K: [bh][n][64]

  // Q^T B-fragments (col=q=lq, k-rows = dc*16 + hi*8 + 0..7)
  bf16x8 qf[4];
  {
    const u16* qp = qws + kbase + (size_t)(q0 + lq) * 64 + hi * 8;
#pragma unroll
    for (int dc = 0; dc < 4; ++dc) qf[dc] = *(const bf16x8*)(qp + dc * 16);
  }

  const f32x16 zc = {};
  f32x16 o0 = {}, o1 = {};   // O^T: d rows 0..31 / 32..63, col q=lq
  float lsum = 0.f;

  // K read offsets (row lq of [32][8 chunks], chunk^=(lq&7)); V read offsets
  // ([wc][d] layout: wc = c*2+hi, d = lq / 32+lq)
  int koff[4], voff[2];
#pragma unroll
  for (int dc = 0; dc < 4; ++dc)
    koff[dc] = lq * 64 + (((dc * 2 + hi) ^ (lq & 7)) * 8);
#pragma unroll
  for (int c = 0; c < 2; ++c)
    voff[c] = (c * 2 + hi) * 512 + lq * 8;

  // staging (identical to R4/R7): pair p stages its K tile (256 slots x 16B)
  // + V tile (256) with its 2 qw-waves; wave qw covers slots [qw*128, +128).
  // K slot s -> (kv = s>>3, ch' = s&7): LDS linear by s; source row pi(kv)
  // (swap bits 2<->3), source chunk ch'^(kv&7). V: linear 4KB blob.
  const int s0i = qw * 128 + ln, s1i = s0i + 64;
  const int kvA = s0i >> 3, kvB = s1i >> 3;
  const int piA = (kvA & ~12) | ((kvA & 4) << 1) | ((kvA & 8) >> 1);
  const int piB = (kvB & ~12) | ((kvB & 4) << 1) | ((kvB & 8) >> 1);
  const u16* kg0 = kws + kbase + (size_t)(kv0 + piA) * 64 + (((s0i & 7) ^ (kvA & 7)) * 8);
  const u16* kg1 = kws + kbase + (size_t)(kv0 + piB) * 64 + (((s1i & 7) ^ (kvB & 7)) * 8);
  const u16* vg  = vtws + ((size_t)bh * 64 + (kv0 >> 5)) * 2048 + s0i * 8;
  u16* Kb = SM + p * 4096;          // + buf*2048
  u16* Vb = SM + 8192 + p * 4096;
  const int sd = qw * 1024;         // wave's slot base (u16) within a buffer

#define STAGE(buf, t) do { \
    GLOAD16(kg0 + (size_t)(t) * 2048, Kb + (buf) * 2048 + sd); \
    GLOAD16(kg1 + (size_t)(t) * 2048, Kb + (buf) * 2048 + sd + 512); \
    GLOAD16(vg + (size_t)(t) * 2048, Vb + (buf) * 2048 + sd); \
    GLOAD16(vg + (size_t)(t) * 2048 + 512, Vb + (buf) * 2048 + sd + 512); \
  } while (0)

  // prologue: stage tile 0 into buffer 0
  STAGE(0, 0);
  __syncthreads();

  int cur = 0;
  for (int it = 0; it < 32; ++it) {
    const int nxt = cur ^ 1;
    if (it + 1 < 32) STAGE(nxt, it + 1);
    const u16* kbuf = Kb + cur * 2048;
    const u16* vbuf = Vb + cur * 2048;

    // S^T[k][q]: A = K-tile rows
    f32x16 s;
    {
      bf16x8 kf = *(const bf16x8*)(kbuf + koff[0]);
      s = __builtin_amdgcn_mfma_f32_32x32x16_bf16(kf, qf[0], zc, 0, 0, 0);
    }
#pragma unroll
    for (int dc = 1; dc < 4; ++dc) {
      bf16x8 kf = *(const bf16x8*)(kbuf + koff[dc]);
      s = __builtin_amdgcn_mfma_f32_32x32x16_bf16(kf, qf[dc], s, 0, 0, 0);
    }

    // P = exp2(S) (shift-invariant softmax); denominator on VALU (2 accums)
    float a = 0.f, b2 = 0.f;
#pragma unroll
    for (int r = 0; r < 16; r += 2) {
      float e0 = __builtin_amdgcn_exp2f(s[r]);     s[r] = e0;     a  += e0;
      float e1 = __builtin_amdgcn_exp2f(s[r + 1]); s[r + 1] = e1; b2 += e1;
    }
    lsum += a + b2;

    // PV: with pi-permuted K rows, chunk c (k = c*16 + hi*8 + {0..7}) is
    // regs [c*8..c*8+7] of s for BOTH hi halves — pure in-lane pack.
#pragma unroll
    for (int c = 0; c < 2; ++c) {
      bf16x8 va = *(const bf16x8*)(vbuf + voff[c]);
      bf16x8 vb2 = *(const bf16x8*)(vbuf + voff[c] + 256);
      const int base = c * 8;
      u32x4 pw = {pack2(s[base + 0], s[base + 1]),
                  pack2(s[base + 2], s[base + 3]),
                  pack2(s[base + 4], s[base + 5]),
                  pack2(s[base + 6], s[base + 7])};
      bf16x8 pfrag = __builtin_bit_cast(bf16x8, pw);
      o0 = __builtin_amdgcn_mfma_f32_32x32x16_bf16(va, pfrag, o0, 0, 0, 0);
      o1 = __builtin_amdgcn_mfma_f32_32x32x16_bf16(vb2, pfrag, o1, 0, 0, 0);
    }
    __syncthreads();
    cur = nxt;
  }
#undef STAGE

  // per-wave denominator: lane holds 16 of 32 k-rows; partner lane ln^32 has
  // the rest (same q = lq). After shfl both lanes hold the half-KV total.
  float lg = lsum + __shfl_xor(lsum, 32);

  // combine KV halves: waves p=1 export (O,l); waves p=0 add + store.
  // Exchange in SM (loop done; last barrier above published all reads).
  // Lane-major [val][lane] layout: 64 lanes consecutive -> 2-way alias only.
  // Region per qw: 2048 f32 O + 64 f32 lg; total 4224 f32 = 16.9KB < 32KB.
  float* ex = (float*)SM + qw * 2048 + ln;
  if (p == 1) {
#pragma unroll
    for (int r = 0; r < 16; ++r) {
      ex[r * 64]        = o0[r];
      ex[(16 + r) * 64] = o1[r];
    }
    ((float*)SM)[4096 + qw * 64 + ln] = lg;
  }
  __syncthreads();
  if (p == 0) {
#pragma unroll
    for (int r = 0; r < 16; ++r) {
      o0[r] += ex[r * 64];
      o1[r] += ex[(16 + r) * 64];
    }
    lg += ((float*)SM)[4096 + qw * 64 + ln];

    const float rl = 1.0f / lg;
    const int b = bh / 12, h = bh % 12;
    u16* orow = aows + (size_t)(b * 2048 + q0 + lq) * 768 + h * 64;
#pragma unroll
    for (int t2 = 0; t2 < 4; ++t2) {
      u32x2 pk0 = {pack2(o0[4 * t2 + 0] * rl, o0[4 * t2 + 1] * rl),
                   pack2(o0[4 * t2 + 2] * rl, o0[4 * t2 + 3] * rl)};
      u32x2 pk1 = {pack2(o1[4 * t2 + 0] * rl, o1[4 * t2 + 1] * rl),
                   pack2(o1[4 * t2 + 2] * rl, o1[4 * t2 + 3] * rl)};
      *(u32x2*)(orow + t2 * 8 + 4 * hi)      = pk0;   // d = 8t2+4hi+r
      *(u32x2*)(orow + 32 + t2 * 8 + 4 * hi) = pk1;   // d = 32+8t2+4hi+r
    }
  }
}

// ---------------------------------------------------------------- launch
extern "C" void kernel_launch(void* const* d_in, const int* in_sizes, int n_in,
                              void* d_out, int out_size, void* d_ws, size_t ws_size,
                              hipStream_t stream) {
  const float* x     = (const float*)d_in[0];
  const float* Wqkv  = (const float*)d_in[1];
  const float* bqkv  = (const float*)d_in[2];
  const float* Wproj = (const float*)d_in[3];
  const float* bproj = (const float*)d_in[4];
  float* out = (float*)d_out;

  u16* xb   = (u16*)d_ws;          // 6291456
  u16* wqb  = xb  + 6291456;       // 1769472
  u16* wpb  = wqb + 1769472;       // 589824
  u16* qws  = wpb + 589824;        // 6291456  [bh][n][64], pre-scaled QSCALE
  u16* kws  = qws + 6291456;       // 6291456  [bh][n][64]
  u16* vtws = kws + 6291456;       // 6291456  [bh][32tile][4wc][64d][8] LDS-ready V^T
  u16* aows = vtws + 6291456;      // 6291456  [b*2048+q][768]

  cvt_all<<<4224, 256, 0, stream>>>(x, Wqkv, Wproj,
                                    (unsigned*)xb, (unsigned*)wqb, (unsigned*)wpb);

  gemm_tn<0><<<dim3(64, 18), 256, 0, stream>>>(xb, wqb, bqkv, nullptr,
                                               qws, kws, vtws, 8192, 2304, 768);
  attn_fa<<<dim3(32, 48), 256, 0, stream>>>(qws, kws, vtws, aows);
  gemm_tn<1><<<dim3(64, 6), 256, 0, stream>>>(aows, wpb, bproj, out,
                                              nullptr, nullptr, nullptr,
                                              8192, 768, 768);
}

// Round 12
// 136.446 us; speedup vs baseline: 1.0601x; 1.0601x over previous
//
#include <hip/hip_runtime.h>

typedef __bf16 bf16x8 __attribute__((ext_vector_type(8)));
typedef __bf16 bf16x2 __attribute__((ext_vector_type(2)));
typedef float  f32x4  __attribute__((ext_vector_type(4)));
typedef float  f32x16 __attribute__((ext_vector_type(16)));
typedef unsigned short u16;
typedef unsigned u32x2 __attribute__((ext_vector_type(2)));
typedef unsigned u32x4 __attribute__((ext_vector_type(4)));

// native RNE f32->bf16 (compiler emits v_cvt_pk_bf16_f32)
__device__ __forceinline__ u16 f2bf(float f) {
  return __builtin_bit_cast(u16, (__bf16)f);
}
// pack two f32 -> dword of 2 bf16 (lo = bits 0-15)
__device__ __forceinline__ unsigned pack2(float lo, float hi) {
  bf16x2 t;
  t[0] = (__bf16)lo; t[1] = (__bf16)hi;
  return __builtin_bit_cast(unsigned, t);
}

#define GLOAD16(g, l) __builtin_amdgcn_global_load_lds( \
    (__attribute__((address_space(1))) void*)(void*)(g), \
    (__attribute__((address_space(3))) void*)(l), 16, 0, 0)

// log2(e)/8 : folds softmax scale (1/sqrt(64)) and exp->exp2 conversion into Q
#define QSCALE 0.18033688011112042f

// ---------------------------------------------------------------- converts
// single segmented launch (boundaries block-uniform: 3072 / 864 / 288 blocks)
__global__ __launch_bounds__(256) void cvt_all(
    const float* __restrict__ x, const float* __restrict__ wq,
    const float* __restrict__ wp, unsigned* __restrict__ xb,
    unsigned* __restrict__ wqb, unsigned* __restrict__ wpb) {
  int i = blockIdx.x * 256 + threadIdx.x;
  const float* src;
  unsigned* dst;
  if (i < 786432) {                 // x: 6291456 f32 = 786432 vec8
    src = x; dst = xb;
  } else if (i < 786432 + 221184) { // Wqkv: 1769472 f32
    src = wq; dst = wqb; i -= 786432;
  } else {                          // Wproj: 589824 f32
    src = wp; dst = wpb; i -= 786432 + 221184;
  }
  const float4* s = (const float4*)src + 2 * (size_t)i;
  float4 a = s[0], b = s[1];
  u32x4 o = {pack2(a.x, a.y), pack2(a.z, a.w), pack2(b.x, b.y), pack2(b.z, b.w)};
  *((u32x4*)dst + i) = o;
}

// ---------------------------------------------------------------- GEMM (TN)
// C[m][n] = sum_k A[m][k]*B[n][k]; 128x128 tile, BK=32, double-buffered LDS,
// one barrier per K-step (stage(next) overlaps compute(cur)).
// R12: T1 XCD-chunked block swizzle — each XCD owns a contiguous 8-block
// M-chunk (1024 rows of A = 1.5MB bf16, L2-resident across all N-panels)
// and streams 0.2MB B-panels with 8x in-XCD reuse. Bijective for any grid
// with gridDim.x%8==0 and total%8==0 (1152 and 384 both qualify).
template<int EPI>
__global__ __launch_bounds__(256) void gemm_tn(
    const u16* __restrict__ A, const u16* __restrict__ B,
    const float* __restrict__ bias, float* __restrict__ outF,
    u16* __restrict__ qws, u16* __restrict__ kws, u16* __restrict__ vtws,
    int M, int N, int K) {
  __shared__ __align__(16) u16 As[8192];   // 2 x [128][32]
  __shared__ __align__(16) u16 Bs[8192];
  const int tid = threadIdx.x;
  const int ln = tid & 63, wv = tid >> 6;
  const int wr = wv >> 1, wc = wv & 1;

  // XCD-chunked swizzle: flat -> (bx, by). xcd = flat&7 owns
  // bx in [xcd*cx, xcd*cx+cx), cx = gridDim.x/8; by iterates per XCD.
  const int flat = (int)(blockIdx.y * gridDim.x + blockIdx.x);
  const int cx = (int)gridDim.x >> 3;
  const int xcd = flat & 7, j = flat >> 3;
  const int bx = xcd * cx + (j % cx);
  const int by = j / cx;
  const int m0 = bx * 128, n0 = by * 128;

  f32x4 acc[4][4] = {};

  const int c0 = tid, c1 = tid + 256;
  const int r0 = c0 >> 2, kc0 = ((c0 & 3) ^ ((r0 >> 1) & 3)) * 8;
  const int r1 = c1 >> 2, kc1 = ((c1 & 3) ^ ((r1 >> 1) & 3)) * 8;
  const u16* ag0 = A + (size_t)(m0 + r0) * K + kc0;
  const u16* ag1 = A + (size_t)(m0 + r1) * K + kc1;
  const u16* bg0 = B + (size_t)(n0 + r0) * K + kc0;
  const u16* bg1 = B + (size_t)(n0 + r1) * K + kc1;

  // prologue: stage k0=0 into buffer 0
  GLOAD16(ag0, As + wv * 512);
  GLOAD16(ag1, As + 2048 + wv * 512);
  GLOAD16(bg0, Bs + wv * 512);
  GLOAD16(bg1, Bs + 2048 + wv * 512);
  __syncthreads();

  int cur = 0;
  for (int k0 = 0; k0 < K; k0 += 32) {
    const int nxt = cur ^ 1;
    if (k0 + 32 < K) {
      GLOAD16(ag0 + k0 + 32, As + nxt * 4096 + wv * 512);
      GLOAD16(ag1 + k0 + 32, As + nxt * 4096 + 2048 + wv * 512);
      GLOAD16(bg0 + k0 + 32, Bs + nxt * 4096 + wv * 512);
      GLOAD16(bg1 + k0 + 32, Bs + nxt * 4096 + 2048 + wv * 512);
    }
    const u16* ab = As + cur * 4096;
    const u16* bb = Bs + cur * 4096;
    bf16x8 af[4], bfr[4];
#pragma unroll
    for (int i = 0; i < 4; ++i) {
      int ra = wr * 64 + i * 16 + (ln & 15);
      af[i] = *(const bf16x8*)(ab + ra * 32 + (((ln >> 4) ^ ((ra >> 1) & 3)) * 8));
      int rb = wc * 64 + i * 16 + (ln & 15);
      bfr[i] = *(const bf16x8*)(bb + rb * 32 + (((ln >> 4) ^ ((rb >> 1) & 3)) * 8));
    }
#pragma unroll
    for (int i = 0; i < 4; ++i)
#pragma unroll
      for (int j2 = 0; j2 < 4; ++j2)
        acc[i][j2] = __builtin_amdgcn_mfma_f32_16x16x32_bf16(af[i], bfr[j2], acc[i][j2], 0, 0, 0);
    __syncthreads();
    cur = nxt;
  }

  if (EPI == 1) {
#pragma unroll
    for (int j2 = 0; j2 < 4; ++j2) {
      int col = n0 + wc * 64 + j2 * 16 + (ln & 15);
      float bj = bias[col];
#pragma unroll
      for (int i = 0; i < 4; ++i) {
        int mr = m0 + wr * 64 + i * 16 + ((ln >> 4) << 2);
#pragma unroll
        for (int r = 0; r < 4; ++r)
          outF[(size_t)(mr + r) * N + col] = acc[i][j2][r] + bj;
      }
    }
  } else {
    const int s = n0 / 768;  // 0=q 1=k 2=v (block-uniform; 768%128==0)
#pragma unroll
    for (int j2 = 0; j2 < 4; ++j2) {
      int col = n0 + wc * 64 + j2 * 16 + (ln & 15);
      float bj = bias[col];
      int ns = col - s * 768;
      int h = ns >> 6, d = ns & 63;
#pragma unroll
      for (int i = 0; i < 4; ++i) {
        int m = m0 + wr * 64 + i * 16 + ((ln >> 4) << 2);
        int b = m >> 11, iseq = m & 2047;
        size_t bh = (size_t)(b * 12 + h);
        if (s == 0) {
#pragma unroll
          for (int r = 0; r < 4; ++r)
            qws[(bh * 2048 + iseq + r) * 64 + d] = f2bf((acc[i][j2][r] + bj) * QSCALE);
        } else if (s == 1) {
#pragma unroll
          for (int r = 0; r < 4; ++r)
            kws[(bh * 2048 + iseq + r) * 64 + d] = f2bf(acc[i][j2][r] + bj);
        } else {
          // V^T in LDS-READY layout: [bh][tile=k>>5][wc=(k>>3)&3][d][j=k&7].
          // Each 32-kv tile is a contiguous 4KB blob whose linear order is
          // exactly what attn's global_load_lds staging needs (dest linear,
          // source linear, fully coalesced both sides).
          u32x2 pk = {pack2(acc[i][j2][0] + bj, acc[i][j2][1] + bj),
                      pack2(acc[i][j2][2] + bj, acc[i][j2][3] + bj)};
          *(u32x2*)(vtws + ((size_t)bh * 64 + (iseq >> 5)) * 2048 +
                    ((iseq >> 3) & 3) * 512 + (size_t)d * 8 + (iseq & 7)) = pk;
        }
      }
    }
  }
}

// ---------------------------------------------------------------- flash attn
// R4 structure (best measured: 62.4us) — final form after the exploration
// ladder: R5 counted-vmcnt null, R6 in-wave pipeline spills, R8 wave-private
// loses staging-sharing, R9 stagger null, R10 LDS-free loses sharing, R11
// occupancy unlock null. Counter fingerprint stable: MFMA ~33%, VALU ~40%,
// LDS ~33%, nothing saturated — chain-bound at this geometry, all named
// mechanisms tested. Structure:
//   - 64q/wave x half-KV pair-split: each K/V LDS fragment feeds 2 q-groups
//   - KVBLK=32, K 4KB + V 4KB per pair, double-buffered -> 33KB, 3 blocks/CU
//   - V staged via async global_load_lds from LDS-ready layout (linear blob)
//   - K rows pi-permuted (swap bits 2<->3) -> PV's P-fragment chunk c is regs
//     [c*8..c*8+7] of s[g] for both hi halves — pure in-lane pack
//   - exp2 shift-invariant softmax (no max tracking), denominator on VALU
//   - KV halves combined by plain (O,l) addition via one LDS exchange
//   - XCD-chunked swizzle: 6 bh per XCD -> K+V working set L2-resident
#define SWZ(v) (((v) & 32) | (((v) & 31) ^ (ln & 31)))
__global__ __launch_bounds__(256, 3) void attn_fa(
    const u16* __restrict__ qws, const u16* __restrict__ kws,
    const u16* __restrict__ vtws, u16* __restrict__ aows) {
  __shared__ __align__(16) u16 SM[16384];  // K: [p][buf][2048] | V: 8192 + same
  __shared__ float Ls[256];                // denominator exchange
  const int tid = threadIdx.x, ln = tid & 63, wv = tid >> 6;
  const int lq = ln & 31, hi = ln >> 5;
  const int qw = wv & 1;        // which 64-q chunk of the block's 128 q
  const int p  = wv >> 1;       // which KV half

  // XCD-chunked swizzle: flat = y*16+x; xcd = flat&7 owns bh in [6*xcd,6*xcd+6)
  const int flat = blockIdx.y * 16 + blockIdx.x;
  const int xcd = flat & 7, jj = flat >> 3;
  const int bh = xcd * 6 + (jj % 6);
  const int q0 = (jj / 6) * 128 + qw * 64;

  const int kv0 = p * 1024;
  const size_t kbase = (size_t)bh * 2048 * 64;   // Q/K: [bh][n][64]

  // Q^T B-fragments, two q-groups (col=q=lq, k-rows = dc*16 + hi*8 + 0..7)
  bf16x8 qf[2][4];
#pragma unroll
  for (int g = 0; g < 2; ++g) {
    const u16* qp = qws + kbase + (size_t)(q0 + g * 32 + lq) * 64 + hi * 8;
#pragma unroll
    for (int dc = 0; dc < 4; ++dc) qf[g][dc] = *(const bf16x8*)(qp + dc * 16);
  }

  const f32x16 zc = {};
  f32x16 o0[2] = {}, o1[2] = {};           // O^T per q-group: d 0..31 / 32..63
  float lsum[2] = {0.f, 0.f};              // denom partial sums

  // K read offsets (row lq of [32][8 chunks], chunk^=(lq&7)); V read offsets
  // ([wc][d] layout: wc = c*2+hi, d = lq / 32+lq)
  int koff[4], voff[2];
#pragma unroll
  for (int dc = 0; dc < 4; ++dc)
    koff[dc] = lq * 64 + (((dc * 2 + hi) ^ (lq & 7)) * 8);
#pragma unroll
  for (int c = 0; c < 2; ++c)
    voff[c] = (c * 2 + hi) * 512 + lq * 8;

  // staging: pair p stages its K tile (256 slots x 16B) + V tile (256) with
  // 128 threads; wave qw covers slots [qw*128, qw*128+128) of each.
  // K slot s -> (kv = s>>3, ch' = s&7): LDS linear by s; source row
  // pi(kv) (swap bits 2<->3), source chunk ch'^(kv&7).
  // V slot s -> source is the linear 4KB tile blob (LDS-ready layout).
  const int s0i = qw * 128 + ln, s1i = s0i + 64;
  const int kvA = s0i >> 3, kvB = s1i >> 3;
  const int piA = (kvA & ~12) | ((kvA & 4) << 1) | ((kvA & 8) >> 1);
  const int piB = (kvB & ~12) | ((kvB & 4) << 1) | ((kvB & 8) >> 1);
  const u16* kg0 = kws + kbase + (size_t)(kv0 + piA) * 64 + (((s0i & 7) ^ (kvA & 7)) * 8);
  const u16* kg1 = kws + kbase + (size_t)(kv0 + piB) * 64 + (((s1i & 7) ^ (kvB & 7)) * 8);
  const u16* vg  = vtws + ((size_t)bh * 64 + (kv0 >> 5)) * 2048 + s0i * 8;
  u16* Kb = SM + p * 4096;          // + buf*2048
  u16* Vb = SM + 8192 + p * 4096;
  const int sd = qw * 1024;         // wave's slot base (u16) within a buffer

#define STAGE(buf, t) do { \
    GLOAD16(kg0 + (size_t)(t) * 2048, Kb + (buf) * 2048 + sd); \
    GLOAD16(kg1 + (size_t)(t) * 2048, Kb + (buf) * 2048 + sd + 512); \
    GLOAD16(vg + (size_t)(t) * 2048, Vb + (buf) * 2048 + sd); \
    GLOAD16(vg + (size_t)(t) * 2048 + 512, Vb + (buf) * 2048 + sd + 512); \
  } while (0)

  // prologue: stage tile 0 into buffer 0
  STAGE(0, 0);
  __syncthreads();

  int cur = 0;
  for (int it = 0; it < 32; ++it) {
    const int nxt = cur ^ 1;
    if (it + 1 < 32) STAGE(nxt, it + 1);
    const u16* kbuf = Kb + cur * 2048;
    const u16* vbuf = Vb + cur * 2048;

    // S^T[k][q]: A = K-tile rows (shared LDS load feeds both q-groups)
    f32x16 s[2];
    {
      bf16x8 kf = *(const bf16x8*)(kbuf + koff[0]);
      s[0] = __builtin_amdgcn_mfma_f32_32x32x16_bf16(kf, qf[0][0], zc, 0, 0, 0);
      s[1] = __builtin_amdgcn_mfma_f32_32x32x16_bf16(kf, qf[1][0], zc, 0, 0, 0);
    }
#pragma unroll
    for (int dc = 1; dc < 4; ++dc) {
      bf16x8 kf = *(const bf16x8*)(kbuf + koff[dc]);
      s[0] = __builtin_amdgcn_mfma_f32_32x32x16_bf16(kf, qf[0][dc], s[0], 0, 0, 0);
      s[1] = __builtin_amdgcn_mfma_f32_32x32x16_bf16(kf, qf[1][dc], s[1], 0, 0, 0);
    }

    // P = exp2(S) (shift-invariant softmax); denominator summed on VALU
#pragma unroll
    for (int g = 0; g < 2; ++g) {
      float a = 0.f;
#pragma unroll
      for (int r = 0; r < 16; ++r) {
        float e = __builtin_amdgcn_exp2f(s[g][r]); s[g][r] = e; a += e;
      }
      lsum[g] += a;
    }

    // PV: V fragments feed both q-groups. With pi-permuted K rows, chunk c
    // (k = c*16 + hi*8 + {0..7}) is regs [c*8..c*8+7] of s[g] for BOTH hi
    // halves — pure in-lane pack, no cross-lane exchange.
#pragma unroll
    for (int c = 0; c < 2; ++c) {
      bf16x8 va = *(const bf16x8*)(vbuf + voff[c]);
      bf16x8 vb2 = *(const bf16x8*)(vbuf + voff[c] + 256);
#pragma unroll
      for (int g = 0; g < 2; ++g) {
        const int base = c * 8;
        u32x4 pw = {pack2(s[g][base + 0], s[g][base + 1]),
                    pack2(s[g][base + 2], s[g][base + 3]),
                    pack2(s[g][base + 4], s[g][base + 5]),
                    pack2(s[g][base + 6], s[g][base + 7])};
        bf16x8 pfrag = __builtin_bit_cast(bf16x8, pw);
        o0[g] = __builtin_amdgcn_mfma_f32_32x32x16_bf16(va, pfrag, o0[g], 0, 0, 0);
        o1[g] = __builtin_amdgcn_mfma_f32_32x32x16_bf16(vb2, pfrag, o1[g], 0, 0, 0);
      }
    }
    __syncthreads();
    cur = nxt;
  }
#undef STAGE

  // per-wave denominator: lane holds 16 of 32 k-rows; partner lane ln^32 has
  // the rest (same q = lq). After shfl both lanes hold the half-KV total.
  float lg[2];
#pragma unroll
  for (int g = 0; g < 2; ++g) {
    lg[g] = lsum[g];
    lg[g] += __shfl_xor(lg[g], 32);
  }

  // combine KV halves: waves p=1 export (O,l); waves p=0 add + store.
  // O exchange packed into SM (32KB = 2 qw-groups x 64 lanes x 64 f32) with
  // XOR swizzle: value v -> col (v&32)|((v&31)^(ln&31)) — conflict-free
  // (lanes ln, ln^32 alias 2-way = free). l goes via Ls.
  float* exO = (float*)SM + qw * 4096 + ln * 64;
  if (p == 1) {
#pragma unroll
    for (int r = 0; r < 16; ++r) {
      exO[SWZ(r)]      = o0[0][r];
      exO[SWZ(16 + r)] = o1[0][r];
      exO[SWZ(32 + r)] = o0[1][r];
      exO[SWZ(48 + r)] = o1[1][r];
    }
    Ls[qw * 128 + ln * 2 + 0] = lg[0];
    Ls[qw * 128 + ln * 2 + 1] = lg[1];
  }
  __syncthreads();
  if (p == 0) {
#pragma unroll
    for (int r = 0; r < 16; ++r) {
      o0[0][r] += exO[SWZ(r)];
      o1[0][r] += exO[SWZ(16 + r)];
      o0[1][r] += exO[SWZ(32 + r)];
      o1[1][r] += exO[SWZ(48 + r)];
    }
    lg[0] += Ls[qw * 128 + ln * 2 + 0];
    lg[1] += Ls[qw * 128 + ln * 2 + 1];

    const int b = bh / 12, h = bh % 12;
#pragma unroll
    for (int g = 0; g < 2; ++g) {
      const float rl = 1.0f / lg[g];
      u16* orow = aows + (size_t)(b * 2048 + q0 + g * 32 + lq) * 768 + h * 64;
#pragma unroll
      for (int t = 0; t < 4; ++t) {
        u32x2 pk0 = {pack2(o0[g][4 * t + 0] * rl, o0[g][4 * t + 1] * rl),
                     pack2(o0[g][4 * t + 2] * rl, o0[g][4 * t + 3] * rl)};
        u32x2 pk1 = {pack2(o1[g][4 * t + 0] * rl, o1[g][4 * t + 1] * rl),
                     pack2(o1[g][4 * t + 2] * rl, o1[g][4 * t + 3] * rl)};
        *(u32x2*)(orow + t * 8 + 4 * hi)      = pk0;   // d = 8t+4hi+r
        *(u32x2*)(orow + 32 + t * 8 + 4 * hi) = pk1;   // d = 32+8t+4hi+r
      }
    }
  }
}

// ---------------------------------------------------------------- launch
extern "C" void kernel_launch(void* const* d_in, const int* in_sizes, int n_in,
                              void* d_out, int out_size, void* d_ws, size_t ws_size,
                              hipStream_t stream) {
  const float* x     = (const float*)d_in[0];
  const float* Wqkv  = (const float*)d_in[1];
  const float* bqkv  = (const float*)d_in[2];
  const float* Wproj = (const float*)d_in[3];
  const float* bproj = (const float*)d_in[4];
  float* out = (float*)d_out;

  u16* xb   = (u16*)d_ws;          // 6291456
  u16* wqb  = xb  + 6291456;       // 1769472
  u16* wpb  = wqb + 1769472;       // 589824
  u16* qws  = wpb + 589824;        // 6291456  [bh][n][64], pre-scaled QSCALE
  u16* kws  = qws + 6291456;       // 6291456  [bh][n][64]
  u16* vtws = kws + 6291456;       // 6291456  [bh][32tile][4wc][64d][8] LDS-ready V^T
  u16* aows = vtws + 6291456;      // 6291456  [b*2048+q][768]

  cvt_all<<<4224, 256, 0, stream>>>(x, Wqkv, Wproj,
                                    (unsigned*)xb, (unsigned*)wqb, (unsigned*)wpb);

  gemm_tn<0><<<dim3(64, 18), 256, 0, stream>>>(xb, wqb, bqkv, nullptr,
                                               qws, kws, vtws, 8192, 2304, 768);
  attn_fa<<<dim3(16, 48), 256, 0, stream>>>(qws, kws, vtws, aows);
  gemm_tn<1><<<dim3(64, 6), 256, 0, stream>>>(aows, wpb, bproj, out,
                                              nullptr, nullptr, nullptr,
                                              8192, 768, 768);
}

// Round 13
// 134.221 us; speedup vs baseline: 1.0777x; 1.0166x over previous
//
#include <hip/hip_runtime.h>

typedef __bf16 bf16x8 __attribute__((ext_vector_type(8)));
typedef __bf16 bf16x2 __attribute__((ext_vector_type(2)));
typedef float  f32x4  __attribute__((ext_vector_type(4)));
typedef float  f32x16 __attribute__((ext_vector_type(16)));
typedef unsigned short u16;
typedef unsigned u32x2 __attribute__((ext_vector_type(2)));
typedef unsigned u32x4 __attribute__((ext_vector_type(4)));

// native RNE f32->bf16 (compiler emits v_cvt_pk_bf16_f32)
__device__ __forceinline__ u16 f2bf(float f) {
  return __builtin_bit_cast(u16, (__bf16)f);
}
// pack two f32 -> dword of 2 bf16 (lo = bits 0-15)
__device__ __forceinline__ unsigned pack2(float lo, float hi) {
  bf16x2 t;
  t[0] = (__bf16)lo; t[1] = (__bf16)hi;
  return __builtin_bit_cast(unsigned, t);
}

#define GLOAD16(g, l) __builtin_amdgcn_global_load_lds( \
    (__attribute__((address_space(1))) void*)(void*)(g), \
    (__attribute__((address_space(3))) void*)(l), 16, 0, 0)

// log2(e)/8 : folds softmax scale (1/sqrt(64)) and exp->exp2 conversion into Q
#define QSCALE 0.18033688011112042f

// ---------------------------------------------------------------- converts
// single segmented launch (boundaries block-uniform: 3072 / 864 / 288 blocks)
__global__ __launch_bounds__(256) void cvt_all(
    const float* __restrict__ x, const float* __restrict__ wq,
    const float* __restrict__ wp, unsigned* __restrict__ xb,
    unsigned* __restrict__ wqb, unsigned* __restrict__ wpb) {
  int i = blockIdx.x * 256 + threadIdx.x;
  const float* src;
  unsigned* dst;
  if (i < 786432) {                 // x: 6291456 f32 = 786432 vec8
    src = x; dst = xb;
  } else if (i < 786432 + 221184) { // Wqkv: 1769472 f32
    src = wq; dst = wqb; i -= 786432;
  } else {                          // Wproj: 589824 f32
    src = wp; dst = wpb; i -= 786432 + 221184;
  }
  const float4* s = (const float4*)src + 2 * (size_t)i;
  float4 a = s[0], b = s[1];
  u32x4 o = {pack2(a.x, a.y), pack2(a.z, a.w), pack2(b.x, b.y), pack2(b.z, b.w)};
  *((u32x4*)dst + i) = o;
}

// ---------------------------------------------------------------- GEMM (TN)
// C[m][n] = sum_k A[m][k]*B[n][k]; 128x128 tile, double-buffered LDS, one
// barrier per BK-step (stage(next) overlaps compute(cur)).
// R13: BK templated. BK=64 is stored/processed as TWO proven BK=32 halves
// ([half][128][32] in LDS, identical swizzle + fragment arithmetic per
// half) — halves the barrier count and doubles MFMA per barrier interval.
// Used for proj (384 blocks = 1.5/CU: barriers maximally exposed at low
// occupancy; 64KB LDS is free there since residency is grid-capped at 1-2
// blocks/CU anyway). gemm0 keeps BK=32 (3-block residency matters there,
// m132 lesson). XCD-chunked swizzle kept from R12 (neutral, harmless).
template<int EPI, int BK>
__global__ __launch_bounds__(256) void gemm_tn(
    const u16* __restrict__ A, const u16* __restrict__ B,
    const float* __restrict__ bias, float* __restrict__ outF,
    u16* __restrict__ qws, u16* __restrict__ kws, u16* __restrict__ vtws,
    int M, int N, int K) {
  constexpr int TSZ = 128 * BK;            // u16 per tile per matrix
  constexpr int NS = BK / 16;              // slot-groups (gloads/thread/matrix)
  __shared__ __align__(16) u16 As[2 * TSZ];
  __shared__ __align__(16) u16 Bs[2 * TSZ];
  const int tid = threadIdx.x;
  const int ln = tid & 63, wv = tid >> 6;
  const int wr = wv >> 1, wc = wv & 1;

  // XCD-chunked swizzle: xcd = flat&7 owns a contiguous bx chunk
  const int flat = (int)(blockIdx.y * gridDim.x + blockIdx.x);
  const int cx = (int)gridDim.x >> 3;
  const int xcd = flat & 7, j = flat >> 3;
  const int bx = xcd * cx + (j % cx);
  const int by = j / cx;
  const int m0 = bx * 128, n0 = by * 128;

  f32x4 acc[4][4] = {};

  // staging: slot s = tid + u*256; half h = s>>9 (k-sub of 32), row
  // r = (s&511)>>2, chunk kc = ((s&3)^((r>>1)&3))*8 + h*32.
  // LDS linear by slot (gload_lds: wave-uniform base + lane*16B).
  // For BK=32 this reduces to the proven R0-R12 arithmetic exactly.
  const u16* ag[NS];
  const u16* bg[NS];
#pragma unroll
  for (int u = 0; u < NS; ++u) {
    int s = tid + u * 256;
    int h = s >> 9, sr = (s & 511) >> 2;
    int kc = ((s & 3) ^ ((sr >> 1) & 3)) * 8 + h * 32;
    ag[u] = A + (size_t)(m0 + sr) * K + kc;
    bg[u] = B + (size_t)(n0 + sr) * K + kc;
  }

  // prologue: stage k0=0 into buffer 0
#pragma unroll
  for (int u = 0; u < NS; ++u) {
    GLOAD16(ag[u], As + u * 2048 + wv * 512);
    GLOAD16(bg[u], Bs + u * 2048 + wv * 512);
  }
  __syncthreads();

  int cur = 0;
  for (int k0 = 0; k0 < K; k0 += BK) {
    const int nxt = cur ^ 1;
    if (k0 + BK < K) {
#pragma unroll
      for (int u = 0; u < NS; ++u) {
        GLOAD16(ag[u] + k0 + BK, As + nxt * TSZ + u * 2048 + wv * 512);
        GLOAD16(bg[u] + k0 + BK, Bs + nxt * TSZ + u * 2048 + wv * 512);
      }
    }
#pragma unroll
    for (int ks = 0; ks < BK / 32; ++ks) {
      const u16* ab = As + cur * TSZ + ks * 4096;
      const u16* bb = Bs + cur * TSZ + ks * 4096;
      bf16x8 af[4], bfr[4];
#pragma unroll
      for (int i = 0; i < 4; ++i) {
        int ra = wr * 64 + i * 16 + (ln & 15);
        af[i] = *(const bf16x8*)(ab + ra * 32 + (((ln >> 4) ^ ((ra >> 1) & 3)) * 8));
        int rb = wc * 64 + i * 16 + (ln & 15);
        bfr[i] = *(const bf16x8*)(bb + rb * 32 + (((ln >> 4) ^ ((rb >> 1) & 3)) * 8));
      }
#pragma unroll
      for (int i = 0; i < 4; ++i)
#pragma unroll
        for (int j2 = 0; j2 < 4; ++j2)
          acc[i][j2] = __builtin_amdgcn_mfma_f32_16x16x32_bf16(af[i], bfr[j2], acc[i][j2], 0, 0, 0);
    }
    __syncthreads();
    cur = nxt;
  }

  if (EPI == 1) {
#pragma unroll
    for (int j2 = 0; j2 < 4; ++j2) {
      int col = n0 + wc * 64 + j2 * 16 + (ln & 15);
      float bj = bias[col];
#pragma unroll
      for (int i = 0; i < 4; ++i) {
        int mr = m0 + wr * 64 + i * 16 + ((ln >> 4) << 2);
#pragma unroll
        for (int r = 0; r < 4; ++r)
          outF[(size_t)(mr + r) * N + col] = acc[i][j2][r] + bj;
      }
    }
  } else {
    const int s = n0 / 768;  // 0=q 1=k 2=v (block-uniform; 768%128==0)
#pragma unroll
    for (int j2 = 0; j2 < 4; ++j2) {
      int col = n0 + wc * 64 + j2 * 16 + (ln & 15);
      float bj = bias[col];
      int ns = col - s * 768;
      int h = ns >> 6, d = ns & 63;
#pragma unroll
      for (int i = 0; i < 4; ++i) {
        int m = m0 + wr * 64 + i * 16 + ((ln >> 4) << 2);
        int b = m >> 11, iseq = m & 2047;
        size_t bh = (size_t)(b * 12 + h);
        if (s == 0) {
#pragma unroll
          for (int r = 0; r < 4; ++r)
            qws[(bh * 2048 + iseq + r) * 64 + d] = f2bf((acc[i][j2][r] + bj) * QSCALE);
        } else if (s == 1) {
#pragma unroll
          for (int r = 0; r < 4; ++r)
            kws[(bh * 2048 + iseq + r) * 64 + d] = f2bf(acc[i][j2][r] + bj);
        } else {
          // V^T in LDS-READY layout: [bh][tile=k>>5][wc=(k>>3)&3][d][j=k&7].
          // Each 32-kv tile is a contiguous 4KB blob whose linear order is
          // exactly what attn's global_load_lds staging needs (dest linear,
          // source linear, fully coalesced both sides).
          u32x2 pk = {pack2(acc[i][j2][0] + bj, acc[i][j2][1] + bj),
                      pack2(acc[i][j2][2] + bj, acc[i][j2][3] + bj)};
          *(u32x2*)(vtws + ((size_t)bh * 64 + (iseq >> 5)) * 2048 +
                    ((iseq >> 3) & 3) * 512 + (size_t)d * 8 + (iseq & 7)) = pk;
        }
      }
    }
  }
}

// ---------------------------------------------------------------- flash attn
// R4 structure (best measured: 62.4us) — final form after the exploration
// ladder: R5 counted-vmcnt null, R6 in-wave pipeline spills, R8 wave-private
// loses staging-sharing, R9 stagger null, R10 LDS-free loses sharing, R11
// occupancy unlock null. Counter fingerprint stable: MFMA ~33%, VALU ~40%,
// LDS ~33%, nothing saturated — chain-bound at this geometry, all named
// mechanisms tested. Structure:
//   - 64q/wave x half-KV pair-split: each K/V LDS fragment feeds 2 q-groups
//   - KVBLK=32, K 4KB + V 4KB per pair, double-buffered -> 33KB, 3 blocks/CU
//   - V staged via async global_load_lds from LDS-ready layout (linear blob)
//   - K rows pi-permuted (swap bits 2<->3) -> PV's P-fragment chunk c is regs
//     [c*8..c*8+7] of s[g] for both hi halves — pure in-lane pack
//   - exp2 shift-invariant softmax (no max tracking), denominator on VALU
//   - KV halves combined by plain (O,l) addition via one LDS exchange
//   - XCD-chunked swizzle: 6 bh per XCD -> K+V working set L2-resident
#define SWZ(v) (((v) & 32) | (((v) & 31) ^ (ln & 31)))
__global__ __launch_bounds__(256, 3) void attn_fa(
    const u16* __restrict__ qws, const u16* __restrict__ kws,
    const u16* __restrict__ vtws, u16* __restrict__ aows) {
  __shared__ __align__(16) u16 SM[16384];  // K: [p][buf][2048] | V: 8192 + same
  __shared__ float Ls[256];                // denominator exchange
  const int tid = threadIdx.x, ln = tid & 63, wv = tid >> 6;
  const int lq = ln & 31, hi = ln >> 5;
  const int qw = wv & 1;        // which 64-q chunk of the block's 128 q
  const int p  = wv >> 1;       // which KV half

  // XCD-chunked swizzle: flat = y*16+x; xcd = flat&7 owns bh in [6*xcd,6*xcd+6)
  const int flat = blockIdx.y * 16 + blockIdx.x;
  const int xcd = flat & 7, jj = flat >> 3;
  const int bh = xcd * 6 + (jj % 6);
  const int q0 = (jj / 6) * 128 + qw * 64;

  const int kv0 = p * 1024;
  const size_t kbase = (size_t)bh * 2048 * 64;   // Q/K: [bh][n][64]

  // Q^T B-fragments, two q-groups (col=q=lq, k-rows = dc*16 + hi*8 + 0..7)
  bf16x8 qf[2][4];
#pragma unroll
  for (int g = 0; g < 2; ++g) {
    const u16* qp = qws + kbase + (size_t)(q0 + g * 32 + lq) * 64 + hi * 8;
#pragma unroll
    for (int dc = 0; dc < 4; ++dc) qf[g][dc] = *(const bf16x8*)(qp + dc * 16);
  }

  const f32x16 zc = {};
  f32x16 o0[2] = {}, o1[2] = {};           // O^T per q-group: d 0..31 / 32..63
  float lsum[2] = {0.f, 0.f};              // denom partial sums

  // K read offsets (row lq of [32][8 chunks], chunk^=(lq&7)); V read offsets
  // ([wc][d] layout: wc = c*2+hi, d = lq / 32+lq)
  int koff[4], voff[2];
#pragma unroll
  for (int dc = 0; dc < 4; ++dc)
    koff[dc] = lq * 64 + (((dc * 2 + hi) ^ (lq & 7)) * 8);
#pragma unroll
  for (int c = 0; c < 2; ++c)
    voff[c] = (c * 2 + hi) * 512 + lq * 8;

  // staging: pair p stages its K tile (256 slots x 16B) + V tile (256) with
  // 128 threads; wave qw covers slots [qw*128, qw*128+128) of each.
  // K slot s -> (kv = s>>3, ch' = s&7): LDS linear by s; source row
  // pi(kv) (swap bits 2<->3), source chunk ch'^(kv&7).
  // V slot s -> source is the linear 4KB tile blob (LDS-ready layout).
  const int s0i = qw * 128 + ln, s1i = s0i + 64;
  const int kvA = s0i >> 3, kvB = s1i >> 3;
  const int piA = (kvA & ~12) | ((kvA & 4) << 1) | ((kvA & 8) >> 1);
  const int piB = (kvB & ~12) | ((kvB & 4) << 1) | ((kvB & 8) >> 1);
  const u16* kg0 = kws + kbase + (size_t)(kv0 + piA) * 64 + (((s0i & 7) ^ (kvA & 7)) * 8);
  const u16* kg1 = kws + kbase + (size_t)(kv0 + piB) * 64 + (((s1i & 7) ^ (kvB & 7)) * 8);
  const u16* vg  = vtws + ((size_t)bh * 64 + (kv0 >> 5)) * 2048 + s0i * 8;
  u16* Kb = SM + p * 4096;          // + buf*2048
  u16* Vb = SM + 8192 + p * 4096;
  const int sd = qw * 1024;         // wave's slot base (u16) within a buffer

#define STAGE(buf, t) do { \
    GLOAD16(kg0 + (size_t)(t) * 2048, Kb + (buf) * 2048 + sd); \
    GLOAD16(kg1 + (size_t)(t) * 2048, Kb + (buf) * 2048 + sd + 512); \
    GLOAD16(vg + (size_t)(t) * 2048, Vb + (buf) * 2048 + sd); \
    GLOAD16(vg + (size_t)(t) * 2048 + 512, Vb + (buf) * 2048 + sd + 512); \
  } while (0)

  // prologue: stage tile 0 into buffer 0
  STAGE(0, 0);
  __syncthreads();

  int cur = 0;
  for (int it = 0; it < 32; ++it) {
    const int nxt = cur ^ 1;
    if (it + 1 < 32) STAGE(nxt, it + 1);
    const u16* kbuf = Kb + cur * 2048;
    const u16* vbuf = Vb + cur * 2048;

    // S^T[k][q]: A = K-tile rows (shared LDS load feeds both q-groups)
    f32x16 s[2];
    {
      bf16x8 kf = *(const bf16x8*)(kbuf + koff[0]);
      s[0] = __builtin_amdgcn_mfma_f32_32x32x16_bf16(kf, qf[0][0], zc, 0, 0, 0);
      s[1] = __builtin_amdgcn_mfma_f32_32x32x16_bf16(kf, qf[1][0], zc, 0, 0, 0);
    }
#pragma unroll
    for (int dc = 1; dc < 4; ++dc) {
      bf16x8 kf = *(const bf16x8*)(kbuf + koff[dc]);
      s[0] = __builtin_amdgcn_mfma_f32_32x32x16_bf16(kf, qf[0][dc], s[0], 0, 0, 0);
      s[1] = __builtin_amdgcn_mfma_f32_32x32x16_bf16(kf, qf[1][dc], s[1], 0, 0, 0);
    }

    // P = exp2(S) (shift-invariant softmax); denominator summed on VALU
#pragma unroll
    for (int g = 0; g < 2; ++g) {
      float a = 0.f;
#pragma unroll
      for (int r = 0; r < 16; ++r) {
        float e = __builtin_amdgcn_exp2f(s[g][r]); s[g][r] = e; a += e;
      }
      lsum[g] += a;
    }

    // PV: V fragments feed both q-groups. With pi-permuted K rows, chunk c
    // (k = c*16 + hi*8 + {0..7}) is regs [c*8..c*8+7] of s[g] for BOTH hi
    // halves — pure in-lane pack, no cross-lane exchange.
#pragma unroll
    for (int c = 0; c < 2; ++c) {
      bf16x8 va = *(const bf16x8*)(vbuf + voff[c]);
      bf16x8 vb2 = *(const bf16x8*)(vbuf + voff[c] + 256);
#pragma unroll
      for (int g = 0; g < 2; ++g) {
        const int base = c * 8;
        u32x4 pw = {pack2(s[g][base + 0], s[g][base + 1]),
                    pack2(s[g][base + 2], s[g][base + 3]),
                    pack2(s[g][base + 4], s[g][base + 5]),
                    pack2(s[g][base + 6], s[g][base + 7])};
        bf16x8 pfrag = __builtin_bit_cast(bf16x8, pw);
        o0[g] = __builtin_amdgcn_mfma_f32_32x32x16_bf16(va, pfrag, o0[g], 0, 0, 0);
        o1[g] = __builtin_amdgcn_mfma_f32_32x32x16_bf16(vb2, pfrag, o1[g], 0, 0, 0);
      }
    }
    __syncthreads();
    cur = nxt;
  }
#undef STAGE

  // per-wave denominator: lane holds 16 of 32 k-rows; partner lane ln^32 has
  // the rest (same q = lq). After shfl both lanes hold the half-KV total.
  float lg[2];
#pragma unroll
  for (int g = 0; g < 2; ++g) {
    lg[g] = lsum[g];
    lg[g] += __shfl_xor(lg[g], 32);
  }

  // combine KV halves: waves p=1 export (O,l); waves p=0 add + store.
  // O exchange packed into SM (32KB = 2 qw-groups x 64 lanes x 64 f32) with
  // XOR swizzle: value v -> col (v&32)|((v&31)^(ln&31)) — conflict-free
  // (lanes ln, ln^32 alias 2-way = free). l goes via Ls.
  float* exO = (float*)SM + qw * 4096 + ln * 64;
  if (p == 1) {
#pragma unroll
    for (int r = 0; r < 16; ++r) {
      exO[SWZ(r)]      = o0[0][r];
      exO[SWZ(16 + r)] = o1[0][r];
      exO[SWZ(32 + r)] = o0[1][r];
      exO[SWZ(48 + r)] = o1[1][r];
    }
    Ls[qw * 128 + ln * 2 + 0] = lg[0];
    Ls[qw * 128 + ln * 2 + 1] = lg[1];
  }
  __syncthreads();
  if (p == 0) {
#pragma unroll
    for (int r = 0; r < 16; ++r) {
      o0[0][r] += exO[SWZ(r)];
      o1[0][r] += exO[SWZ(16 + r)];
      o0[1][r] += exO[SWZ(32 + r)];
      o1[1][r] += exO[SWZ(48 + r)];
    }
    lg[0] += Ls[qw * 128 + ln * 2 + 0];
    lg[1] += Ls[qw * 128 + ln * 2 + 1];

    const int b = bh / 12, h = bh % 12;
#pragma unroll
    for (int g = 0; g < 2; ++g) {
      const float rl = 1.0f / lg[g];
      u16* orow = aows + (size_t)(b * 2048 + q0 + g * 32 + lq) * 768 + h * 64;
#pragma unroll
      for (int t = 0; t < 4; ++t) {
        u32x2 pk0 = {pack2(o0[g][4 * t + 0] * rl, o0[g][4 * t + 1] * rl),
                     pack2(o0[g][4 * t + 2] * rl, o0[g][4 * t + 3] * rl)};
        u32x2 pk1 = {pack2(o1[g][4 * t + 0] * rl, o1[g][4 * t + 1] * rl),
                     pack2(o1[g][4 * t + 2] * rl, o1[g][4 * t + 3] * rl)};
        *(u32x2*)(orow + t * 8 + 4 * hi)      = pk0;   // d = 8t+4hi+r
        *(u32x2*)(orow + 32 + t * 8 + 4 * hi) = pk1;   // d = 32+8t+4hi+r
      }
    }
  }
}

// ---------------------------------------------------------------- launch
extern "C" void kernel_launch(void* const* d_in, const int* in_sizes, int n_in,
                              void* d_out, int out_size, void* d_ws, size_t ws_size,
                              hipStream_t stream) {
  const float* x     = (const float*)d_in[0];
  const float* Wqkv  = (const float*)d_in[1];
  const float* bqkv  = (const float*)d_in[2];
  const float* Wproj = (const float*)d_in[3];
  const float* bproj = (const float*)d_in[4];
  float* out = (float*)d_out;

  u16* xb   = (u16*)d_ws;          // 6291456
  u16* wqb  = xb  + 6291456;       // 1769472
  u16* wpb  = wqb + 1769472;       // 589824
  u16* qws  = wpb + 589824;        // 6291456  [bh][n][64], pre-scaled QSCALE
  u16* kws  = qws + 6291456;       // 6291456  [bh][n][64]
  u16* vtws = kws + 6291456;       // 6291456  [bh][32tile][4wc][64d][8] LDS-ready V^T
  u16* aows = vtws + 6291456;      // 6291456  [b*2048+q][768]

  cvt_all<<<4224, 256, 0, stream>>>(x, Wqkv, Wproj,
                                    (unsigned*)xb, (unsigned*)wqb, (unsigned*)wpb);

  gemm_tn<0, 32><<<dim3(64, 18), 256, 0, stream>>>(xb, wqb, bqkv, nullptr,
                                                   qws, kws, vtws, 8192, 2304, 768);
  attn_fa<<<dim3(16, 48), 256, 0, stream>>>(qws, kws, vtws, aows);
  gemm_tn<1, 64><<<dim3(64, 6), 256, 0, stream>>>(aows, wpb, bproj, out,
                                                  nullptr, nullptr, nullptr,
                                                  8192, 768, 768);
}